// Round 7
// baseline (156.142 us; speedup 1.0000x reference)
//
#include <hip/hip_runtime.h>
#include <math.h>

#define NS 512
#define DE 512
#define NCL 5
#define KSPLIT 16
#define PART_ELEMS (KSPLIT * NS * NS)
#define NBLK 256

// ctrl words: [0]=gsum(f32) [1]=gnz [2]=bar [3]=ticket  (zeroed by memset node)

union SMem {
    struct { float4 As4[128][8]; float4 Bs4[128][8]; } g;      // 32 KB
    struct {
        float4 v4sA[NS / 4], v4sB[NS / 4];                      // 4 KB
        float  ckA[NS], ckB[NS];                                // 4 KB
        float  rn_s[NS];                                        // 2 KB
        int    pkA[NS], pkB[NS];                                // 4 KB
        float  spart[NS * 17];                                  // 34 KB
        float  redf[256];
        int    redi[256];
        unsigned int pcA, pcB;
    } l;                                                        // ~51 KB
};

// ---------------------------------------------------------------------------
// Fused: phase 1 = split-K gram partial (128x128 tile, K=32, XOR-swizzled
// LDS; diagonal tiles emit dpart). Load-spin grid barrier. Phase 2 = loss
// for anchors b, b+256 (R6 structure). Ticket finalize.
// ---------------------------------------------------------------------------
__global__ __launch_bounds__(256) void k_fused(const float* __restrict__ pred,
                                               const int* __restrict__ target,
                                               const float* __restrict__ draw,
                                               float* __restrict__ part,
                                               float* __restrict__ dpart,
                                               unsigned int* __restrict__ ctrl,
                                               float* __restrict__ out) {
    __shared__ SMem sm;
    const int tid = threadIdx.x;
    const int b = blockIdx.x;

    // ================= phase 1: gram partial =================
    {
        const int t = b >> 4, z = b & 15;
        const int row0 = (t >> 2) * 128, col0 = (t & 3) * 128;
        const int kz0 = z * 32;

        const int lr = tid >> 1;
        const int sbase = (tid & 1) * 4;
        const int swz = (lr >> 3) & 7;
        const float4* gA = (const float4*)&pred[(row0 + lr) * DE + kz0];
        const float4* gB = (const float4*)&pred[(col0 + lr) * DE + kz0];
#pragma unroll
        for (int q = 0; q < 4; q++) {
            int s = sbase + q;
            sm.g.As4[lr][s ^ swz] = gA[s];
            sm.g.Bs4[lr][s ^ swz] = gB[s];
        }
        __syncthreads();

        const int tx = tid & 15, ty = tid >> 4;
        const int aswz = ty & 7, bswz = tx & 7;
        float acc[8][8] = {};
#pragma unroll
        for (int q = 0; q < 8; q++) {
            float4 b4[8];
#pragma unroll
            for (int c = 0; c < 8; c++) b4[c] = sm.g.Bs4[tx * 8 + c][q ^ bswz];
#pragma unroll
            for (int rr = 0; rr < 2; rr++) {
                float4 a4[4];
#pragma unroll
                for (int r = 0; r < 4; r++) a4[r] = sm.g.As4[ty * 8 + rr * 4 + r][q ^ aswz];
#pragma unroll
                for (int r = 0; r < 4; r++) {
#pragma unroll
                    for (int c = 0; c < 8; c++) {
                        float v = acc[rr * 4 + r][c];
                        v = fmaf(a4[r].x, b4[c].x, v);
                        v = fmaf(a4[r].y, b4[c].y, v);
                        v = fmaf(a4[r].z, b4[c].z, v);
                        v = fmaf(a4[r].w, b4[c].w, v);
                        acc[rr * 4 + r][c] = v;
                    }
                }
            }
        }
        float* op = part + (size_t)z * NS * NS;
#pragma unroll
        for (int m = 0; m < 8; m++) {
            float4 o0 = make_float4(acc[m][0], acc[m][1], acc[m][2], acc[m][3]);
            float4 o1 = make_float4(acc[m][4], acc[m][5], acc[m][6], acc[m][7]);
            float* dst = &op[(row0 + ty * 8 + m) * NS + col0 + tx * 8];
            *(float4*)dst = o0;
            *(float4*)(dst + 4) = o1;
        }
        if ((t >> 2) == (t & 3) && ty == tx) {
#pragma unroll
            for (int m = 0; m < 8; m++)
                dpart[z * NS + row0 + ty * 8 + m] = acc[m][m];
        }
    }

    // ================= grid barrier: RMW arrive, LOAD spin =================
    {
        __threadfence();                 // release part/dpart stores device-scope
        __syncthreads();
        if (tid == 0) {
            unsigned int* bar = ctrl + 2;
            atomicAdd(bar, 1u);          // one fire-and-forget RMW per block
            while (__hip_atomic_load(bar, __ATOMIC_ACQUIRE,
                                     __HIP_MEMORY_SCOPE_AGENT) < (unsigned int)NBLK)
                __builtin_amdgcn_s_sleep(4);
        }
        __syncthreads();
        __threadfence();                 // acquire before reading remote part
    }

    // ================= phase 2: loss for anchors b, b+256 =================
    const int iA = b, iB = b + 256;
    float* gsum = (float*)ctrl;
    unsigned int* gnz    = ctrl + 1;
    unsigned int* ticket = ctrl + 3;

    // rn from diag partials (once per block)
    float2 d2 = make_float2(0.0f, 0.0f);
#pragma unroll
    for (int z = 0; z < KSPLIT; z++) {
        float2 t2 = ((const float2*)&dpart[z * NS])[tid];
        d2.x += t2.x; d2.y += t2.y;
    }
    const float rn0 = 1.0f / fmaxf(sqrtf(d2.x), 1e-8f);
    const float rn1 = 1.0f / fmaxf(sqrtf(d2.y), 1e-8f);
    const int j0 = tid * 2;
    sm.l.rn_s[j0] = rn0; sm.l.rn_s[j0 + 1] = rn1;
    if (tid == 0) { sm.l.pcA = 0u; sm.l.pcB = 0u; }

    // both anchors' cos rows, loads interleaved for MLP
    float2 gA2 = make_float2(0.0f, 0.0f), gB2 = make_float2(0.0f, 0.0f);
#pragma unroll
    for (int z = 0; z < KSPLIT; z++) {
        const float* base = part + (size_t)z * NS * NS;
        float2 tA = ((const float2*)&base[(size_t)iA * NS])[tid];
        float2 tB = ((const float2*)&base[(size_t)iB * NS])[tid];
        gA2.x += tA.x; gA2.y += tA.y;
        gB2.x += tB.x; gB2.y += tB.y;
    }

    float cp[NCL];
    cp[0] = 0.0f;
#pragma unroll
    for (int c = 0; c < NCL - 1; c++) cp[c + 1] = cp[c] + log1pf(expf(draw[c]));
    const int tiA = target[iA], tiB = target[iB];
    const float cpA = cp[tiA], cpB = cp[tiB];
    __syncthreads();

    const float rniA = sm.l.rn_s[iA], rniB = sm.l.rn_s[iB];
    const int tj0 = target[j0], tj1 = target[j0 + 1];
    const float cpj0 = cp[tj0], cpj1 = cp[tj1];

    {   // anchor A setup
        float c0 = gA2.x * rniA * rn0;
        float c1 = gA2.y * rniA * rn1;
        bool n0 = (tj0 != tiA), n1 = (tj1 != tiA);
        sm.l.ckA[j0] = c0; sm.l.ckA[j0 + 1] = c1;
        ((float2*)sm.l.v4sA)[tid] = make_float2(n0 ? (c0 + fabsf(cpA - cpj0)) : -1e30f,
                                                n1 ? (c1 + fabsf(cpA - cpj1)) : -1e30f);
        if (!n0 && j0 != iA)     sm.l.pkA[atomicAdd(&sm.l.pcA, 1u)] = j0;
        if (!n1 && j0 + 1 != iA) sm.l.pkA[atomicAdd(&sm.l.pcA, 1u)] = j0 + 1;
        sm.l.redi[tid] = ((n0 ? 1 : 0) + (n1 ? 1 : 0));
    }
    {   // anchor B setup (negcounts packed: A low 16, B high 16)
        float c0 = gB2.x * rniB * rn0;
        float c1 = gB2.y * rniB * rn1;
        bool n0 = (tj0 != tiB), n1 = (tj1 != tiB);
        sm.l.ckB[j0] = c0; sm.l.ckB[j0 + 1] = c1;
        ((float2*)sm.l.v4sB)[tid] = make_float2(n0 ? (c0 + fabsf(cpB - cpj0)) : -1e30f,
                                                n1 ? (c1 + fabsf(cpB - cpj1)) : -1e30f);
        if (!n0 && j0 != iB)     sm.l.pkB[atomicAdd(&sm.l.pcB, 1u)] = j0;
        if (!n1 && j0 + 1 != iB) sm.l.pkB[atomicAdd(&sm.l.pcB, 1u)] = j0 + 1;
        sm.l.redi[tid] += ((n0 ? 1 : 0) + (n1 ? 1 : 0)) << 16;
    }
    __syncthreads();
    for (int s = 128; s > 0; s >>= 1) {
        if (tid < s) sm.l.redi[tid] += sm.l.redi[tid + s];
        __syncthreads();
    }
    const int negA = sm.l.redi[0] & 0xffff;
    const int negB = sm.l.redi[0] >> 16;
    const unsigned int nposA = sm.l.pcA, nposB = sm.l.pcB;
    __syncthreads();

    const int kl = tid & 15, jc = tid >> 4;
    const float denA = (float)(negA > 1 ? negA : 1);
    const float denB = (float)(negB > 1 ? negB : 1);
    float contrib = 0.0f;
    int nzc = 0;

    {   // anchor A
        float4 vj[8];
#pragma unroll
        for (int t = 0; t < 8; t++) vj[t] = sm.l.v4sA[jc * 8 + t];
        for (unsigned int p = kl; p < nposA; p += 16) {
            const float ckp = sm.l.ckA[sm.l.pkA[p]];
            float s0 = 0.0f, s1 = 0.0f;
#pragma unroll
            for (int t = 0; t < 8; t++) {
                float4 w = vj[t];
                s0 += fmaxf(w.x - ckp, 0.0f) + fmaxf(w.y - ckp, 0.0f);
                s1 += fmaxf(w.z - ckp, 0.0f) + fmaxf(w.w - ckp, 0.0f);
            }
            sm.l.spart[p * 17 + jc] = s0 + s1;
        }
        __syncthreads();
        for (unsigned int p = tid; p < nposA; p += 256) {
            float s = 0.0f;
#pragma unroll
            for (int q = 0; q < 16; q++) s += sm.l.spart[p * 17 + q];
            contrib += s / denA;
            if (s != 0.0f) nzc++;
        }
        __syncthreads();
    }
    {   // anchor B
        float4 vj[8];
#pragma unroll
        for (int t = 0; t < 8; t++) vj[t] = sm.l.v4sB[jc * 8 + t];
        for (unsigned int p = kl; p < nposB; p += 16) {
            const float ckp = sm.l.ckB[sm.l.pkB[p]];
            float s0 = 0.0f, s1 = 0.0f;
#pragma unroll
            for (int t = 0; t < 8; t++) {
                float4 w = vj[t];
                s0 += fmaxf(w.x - ckp, 0.0f) + fmaxf(w.y - ckp, 0.0f);
                s1 += fmaxf(w.z - ckp, 0.0f) + fmaxf(w.w - ckp, 0.0f);
            }
            sm.l.spart[p * 17 + jc] = s0 + s1;
        }
        __syncthreads();
        for (unsigned int p = tid; p < nposB; p += 256) {
            float s = 0.0f;
#pragma unroll
            for (int q = 0; q < 16; q++) s += sm.l.spart[p * 17 + q];
            contrib += s / denB;
            if (s != 0.0f) nzc++;
        }
    }

    // ================= combined reduction + ticket finalize =================
    sm.l.redf[tid] = contrib;
    sm.l.redi[tid] = nzc;
    __syncthreads();
    for (int s = 128; s > 0; s >>= 1) {
        if (tid < s) { sm.l.redf[tid] += sm.l.redf[tid + s]; sm.l.redi[tid] += sm.l.redi[tid + s]; }
        __syncthreads();
    }
    if (tid == 0) {
        if (sm.l.redf[0] != 0.0f || sm.l.redi[0] != 0) {
            atomicAdd(gsum, sm.l.redf[0]);
            atomicAdd(gnz, (unsigned int)sm.l.redi[0]);
        }
        __threadfence();
        unsigned int t = atomicAdd(ticket, 1u);
        if (t == (unsigned int)(NBLK - 1)) {
            float s = atomicAdd(gsum, 0.0f);
            unsigned int n = atomicAdd(gnz, 0u);
            out[0] = s / (float)(n > 1u ? n : 1u);
        }
    }
}

extern "C" void kernel_launch(void* const* d_in, const int* in_sizes, int n_in,
                              void* d_out, int out_size, void* d_ws, size_t ws_size,
                              hipStream_t stream) {
    const float* pred   = (const float*)d_in[0];
    const float* draw   = (const float*)d_in[1];
    const int*   target = (const int*)d_in[2];
    float* out = (float*)d_out;

    float* ws    = (float*)d_ws;
    float* part  = ws;                                          // 16 MB
    float* dpart = ws + PART_ELEMS;                             // 16*512 floats
    unsigned int* ctrl = (unsigned int*)(dpart + KSPLIT * NS);  // 4 words

    hipMemsetAsync(ctrl, 0, 4 * sizeof(unsigned int), stream);
    hipLaunchKernelGGL(k_fused, dim3(NBLK), dim3(256), 0, stream,
                       pred, target, draw, part, dpart, ctrl, out);
}

// Round 8
// 104.207 us; speedup vs baseline: 1.4984x; 1.4984x over previous
//
#include <hip/hip_runtime.h>
#include <math.h>

#define NS 512
#define DE 512
#define NCL 5
#define NBLK 256

// ctrl words: [0]=gsum(f32) [1]=gnz [2]=ticket [3]=spare  (zeroed by memset node)

// ---------------------------------------------------------------------------
// Single fused kernel. Block b handles anchors iA=b, iB=b+256.
//  - anchor rows staged in LDS (4 KB)
//  - thread tid owns rows j0=2tid, j0+1: streams them once from global
//    (L2/L3-resident, 1 MB total) computing dot(j,A), dot(j,B), dot(j,j)
//  - rn from self-dots (block-local, no cross-block exchange)
//  - R6-proven loss phase: v/ck/pk compaction, 16x16 pass1, pass2,
//    combined reduction, global atomic + ticket finalize
// No intermediate global buffers -> no 16 MB coherence round trip.
// ---------------------------------------------------------------------------
__global__ __launch_bounds__(256) void k_all(const float* __restrict__ pred,
                                             const int* __restrict__ target,
                                             const float* __restrict__ draw,
                                             unsigned int* __restrict__ ctrl,
                                             float* __restrict__ out) {
    const int b = blockIdx.x;
    const int tid = threadIdx.x;
    const int iA = b, iB = b + 256;

    __shared__ float4 sA4[DE / 4], sB4[DE / 4];        // anchor rows, 4 KB
    __shared__ float  rn_s[NS];
    __shared__ float4 v4sA[NS / 4], v4sB[NS / 4];
    __shared__ float  ckA[NS], ckB[NS];
    __shared__ int    pkA[NS], pkB[NS];
    __shared__ float  spart[NS * 17];                  // 34 KB
    __shared__ float  redf[256];
    __shared__ int    redi[256];
    __shared__ unsigned int pcA, pcB;

    float* gsum = (float*)ctrl;
    unsigned int* gnz    = ctrl + 1;
    unsigned int* ticket = ctrl + 2;

    // ---- stage anchor rows ----
    if (tid < 128) sA4[tid]       = ((const float4*)&pred[(size_t)iA * DE])[tid];
    else           sB4[tid - 128] = ((const float4*)&pred[(size_t)iB * DE])[tid - 128];
    if (tid == 0) { pcA = 0u; pcB = 0u; }
    __syncthreads();

    // ---- three dots per owned row (j0, j0+1) ----
    const int j0 = tid * 2;
    const float4* r0 = (const float4*)&pred[(size_t)j0 * DE];
    const float4* r1 = (const float4*)&pred[(size_t)(j0 + 1) * DE];

    float4 aA0 = {0,0,0,0}, aA1 = {0,0,0,0};
    float4 aB0 = {0,0,0,0}, aB1 = {0,0,0,0};
    float4 aS0 = {0,0,0,0}, aS1 = {0,0,0,0};
#pragma unroll 4
    for (int k = 0; k < DE / 4; k++) {
        float4 x0 = r0[k], x1 = r1[k];
        float4 a = sA4[k], bb = sB4[k];
        aA0.x = fmaf(x0.x, a.x, aA0.x);  aA0.y = fmaf(x0.y, a.y, aA0.y);
        aA0.z = fmaf(x0.z, a.z, aA0.z);  aA0.w = fmaf(x0.w, a.w, aA0.w);
        aA1.x = fmaf(x1.x, a.x, aA1.x);  aA1.y = fmaf(x1.y, a.y, aA1.y);
        aA1.z = fmaf(x1.z, a.z, aA1.z);  aA1.w = fmaf(x1.w, a.w, aA1.w);
        aB0.x = fmaf(x0.x, bb.x, aB0.x); aB0.y = fmaf(x0.y, bb.y, aB0.y);
        aB0.z = fmaf(x0.z, bb.z, aB0.z); aB0.w = fmaf(x0.w, bb.w, aB0.w);
        aB1.x = fmaf(x1.x, bb.x, aB1.x); aB1.y = fmaf(x1.y, bb.y, aB1.y);
        aB1.z = fmaf(x1.z, bb.z, aB1.z); aB1.w = fmaf(x1.w, bb.w, aB1.w);
        aS0.x = fmaf(x0.x, x0.x, aS0.x); aS0.y = fmaf(x0.y, x0.y, aS0.y);
        aS0.z = fmaf(x0.z, x0.z, aS0.z); aS0.w = fmaf(x0.w, x0.w, aS0.w);
        aS1.x = fmaf(x1.x, x1.x, aS1.x); aS1.y = fmaf(x1.y, x1.y, aS1.y);
        aS1.z = fmaf(x1.z, x1.z, aS1.z); aS1.w = fmaf(x1.w, x1.w, aS1.w);
    }
    const float dA0 = aA0.x + aA0.y + aA0.z + aA0.w;
    const float dA1 = aA1.x + aA1.y + aA1.z + aA1.w;
    const float dB0 = aB0.x + aB0.y + aB0.z + aB0.w;
    const float dB1 = aB1.x + aB1.y + aB1.z + aB1.w;
    const float ns0 = aS0.x + aS0.y + aS0.z + aS0.w;
    const float ns1 = aS1.x + aS1.y + aS1.z + aS1.w;
    const float rn0 = 1.0f / fmaxf(sqrtf(ns0), 1e-8f);
    const float rn1 = 1.0f / fmaxf(sqrtf(ns1), 1e-8f);
    rn_s[j0] = rn0; rn_s[j0 + 1] = rn1;

    // ordinal class positions
    float cp[NCL];
    cp[0] = 0.0f;
#pragma unroll
    for (int c = 0; c < NCL - 1; c++) cp[c + 1] = cp[c] + log1pf(expf(draw[c]));
    const int tiA = target[iA], tiB = target[iB];
    const float cpA = cp[tiA], cpB = cp[tiB];
    const int tj0 = target[j0], tj1 = target[j0 + 1];
    const float cpj0 = cp[tj0], cpj1 = cp[tj1];
    __syncthreads();

    const float rniA = rn_s[iA], rniB = rn_s[iB];

    {   // anchor A setup
        float c0 = dA0 * rniA * rn0;
        float c1 = dA1 * rniA * rn1;
        bool n0 = (tj0 != tiA), n1 = (tj1 != tiA);
        ckA[j0] = c0; ckA[j0 + 1] = c1;
        ((float2*)v4sA)[tid] = make_float2(n0 ? (c0 + fabsf(cpA - cpj0)) : -1e30f,
                                           n1 ? (c1 + fabsf(cpA - cpj1)) : -1e30f);
        if (!n0 && j0 != iA)     pkA[atomicAdd(&pcA, 1u)] = j0;
        if (!n1 && j0 + 1 != iA) pkA[atomicAdd(&pcA, 1u)] = j0 + 1;
        redi[tid] = ((n0 ? 1 : 0) + (n1 ? 1 : 0));
    }
    {   // anchor B setup (negcounts packed: A low 16, B high 16)
        float c0 = dB0 * rniB * rn0;
        float c1 = dB1 * rniB * rn1;
        bool n0 = (tj0 != tiB), n1 = (tj1 != tiB);
        ckB[j0] = c0; ckB[j0 + 1] = c1;
        ((float2*)v4sB)[tid] = make_float2(n0 ? (c0 + fabsf(cpB - cpj0)) : -1e30f,
                                           n1 ? (c1 + fabsf(cpB - cpj1)) : -1e30f);
        if (!n0 && j0 != iB)     pkB[atomicAdd(&pcB, 1u)] = j0;
        if (!n1 && j0 + 1 != iB) pkB[atomicAdd(&pcB, 1u)] = j0 + 1;
        redi[tid] += ((n0 ? 1 : 0) + (n1 ? 1 : 0)) << 16;
    }
    __syncthreads();
    for (int s = 128; s > 0; s >>= 1) {
        if (tid < s) redi[tid] += redi[tid + s];
        __syncthreads();
    }
    const int negA = redi[0] & 0xffff;
    const int negB = redi[0] >> 16;
    const unsigned int nposA = pcA, nposB = pcB;
    __syncthreads();

    const int kl = tid & 15, jc = tid >> 4;
    const float denA = (float)(negA > 1 ? negA : 1);
    const float denB = (float)(negB > 1 ? negB : 1);
    float contrib = 0.0f;
    int nzc = 0;

    {   // anchor A
        float4 vj[8];
#pragma unroll
        for (int t = 0; t < 8; t++) vj[t] = v4sA[jc * 8 + t];
        for (unsigned int p = kl; p < nposA; p += 16) {
            const float ckp = ckA[pkA[p]];
            float s0 = 0.0f, s1 = 0.0f;
#pragma unroll
            for (int t = 0; t < 8; t++) {
                float4 w = vj[t];
                s0 += fmaxf(w.x - ckp, 0.0f) + fmaxf(w.y - ckp, 0.0f);
                s1 += fmaxf(w.z - ckp, 0.0f) + fmaxf(w.w - ckp, 0.0f);
            }
            spart[p * 17 + jc] = s0 + s1;
        }
        __syncthreads();
        for (unsigned int p = tid; p < nposA; p += 256) {
            float s = 0.0f;
#pragma unroll
            for (int q = 0; q < 16; q++) s += spart[p * 17 + q];
            contrib += s / denA;
            if (s != 0.0f) nzc++;
        }
        __syncthreads();
    }
    {   // anchor B
        float4 vj[8];
#pragma unroll
        for (int t = 0; t < 8; t++) vj[t] = v4sB[jc * 8 + t];
        for (unsigned int p = kl; p < nposB; p += 16) {
            const float ckp = ckB[pkB[p]];
            float s0 = 0.0f, s1 = 0.0f;
#pragma unroll
            for (int t = 0; t < 8; t++) {
                float4 w = vj[t];
                s0 += fmaxf(w.x - ckp, 0.0f) + fmaxf(w.y - ckp, 0.0f);
                s1 += fmaxf(w.z - ckp, 0.0f) + fmaxf(w.w - ckp, 0.0f);
            }
            spart[p * 17 + jc] = s0 + s1;
        }
        __syncthreads();
        for (unsigned int p = tid; p < nposB; p += 256) {
            float s = 0.0f;
#pragma unroll
            for (int q = 0; q < 16; q++) s += spart[p * 17 + q];
            contrib += s / denB;
            if (s != 0.0f) nzc++;
        }
    }

    // ---- combined reduction + ticket finalize ----
    redf[tid] = contrib;
    redi[tid] = nzc;
    __syncthreads();
    for (int s = 128; s > 0; s >>= 1) {
        if (tid < s) { redf[tid] += redf[tid + s]; redi[tid] += redi[tid + s]; }
        __syncthreads();
    }
    if (tid == 0) {
        if (redf[0] != 0.0f || redi[0] != 0) {
            atomicAdd(gsum, redf[0]);
            atomicAdd(gnz, (unsigned int)redi[0]);
        }
        __threadfence();
        unsigned int t = atomicAdd(ticket, 1u);
        if (t == (unsigned int)(NBLK - 1)) {
            float s = atomicAdd(gsum, 0.0f);
            unsigned int n = atomicAdd(gnz, 0u);
            out[0] = s / (float)(n > 1u ? n : 1u);
        }
    }
}

extern "C" void kernel_launch(void* const* d_in, const int* in_sizes, int n_in,
                              void* d_out, int out_size, void* d_ws, size_t ws_size,
                              hipStream_t stream) {
    const float* pred   = (const float*)d_in[0];
    const float* draw   = (const float*)d_in[1];
    const int*   target = (const int*)d_in[2];
    float* out = (float*)d_out;

    unsigned int* ctrl = (unsigned int*)d_ws;   // 4 words, only ws use

    hipMemsetAsync(ctrl, 0, 4 * sizeof(unsigned int), stream);
    hipLaunchKernelGGL(k_all, dim3(NBLK), dim3(256), 0, stream,
                       pred, target, draw, ctrl, out);
}

// Round 9
// 103.447 us; speedup vs baseline: 1.5094x; 1.0074x over previous
//
#include <hip/hip_runtime.h>
#include <math.h>

#define NS 512
#define DE 512
#define NCL 5
#define NBLK 256

// ctrl words: [0]=gsum(f32) [1]=gnz [2]=ticket [3]=spare  (zeroed by memset node)

// ---------------------------------------------------------------------------
// Single fused kernel, 512 threads/block (8 waves = 2/SIMD for latency
// hiding). Block b handles anchors iA=b, iB=b+256. Thread tid owns row j=tid:
// streams it once from L2/L3-resident pred computing dot(j,A), dot(j,B),
// dot(j,j). Then block-local loss (32 k-lanes x 16 j-chunks) + ticket
// finalize. No intermediate global buffers.
// ---------------------------------------------------------------------------
__global__ __launch_bounds__(512) void k_all(const float* __restrict__ pred,
                                             const int* __restrict__ target,
                                             const float* __restrict__ draw,
                                             unsigned int* __restrict__ ctrl,
                                             float* __restrict__ out) {
    const int b = blockIdx.x;
    const int tid = threadIdx.x;
    const int iA = b, iB = b + 256;

    __shared__ float4 sA4[DE / 4], sB4[DE / 4];        // anchor rows, 4 KB
    __shared__ float  rn_s[NS];
    __shared__ float4 v4sA[NS / 4], v4sB[NS / 4];
    __shared__ float  ckA[NS], ckB[NS];
    __shared__ int    pkA[NS], pkB[NS];
    __shared__ float  spart[NS * 17];                  // 34 KB
    __shared__ float  redf[512];
    __shared__ int    redi[512];
    __shared__ unsigned int pcA, pcB;

    float* gsum = (float*)ctrl;
    unsigned int* gnz    = ctrl + 1;
    unsigned int* ticket = ctrl + 2;

    // ---- stage anchor rows ----
    if (tid < 128)                  sA4[tid]       = ((const float4*)&pred[(size_t)iA * DE])[tid];
    else if (tid < 256)             sB4[tid - 128] = ((const float4*)&pred[(size_t)iB * DE])[tid - 128];
    if (tid == 0) { pcA = 0u; pcB = 0u; }
    __syncthreads();

    // ---- three dots for owned row j = tid ----
    const int j = tid;
    const float4* rj = (const float4*)&pred[(size_t)j * DE];

    float4 aA = {0,0,0,0}, aB = {0,0,0,0}, aS = {0,0,0,0};
#pragma unroll 16
    for (int k = 0; k < DE / 4; k++) {
        float4 x = rj[k];
        float4 a = sA4[k], bb = sB4[k];
        aA.x = fmaf(x.x, a.x, aA.x);  aA.y = fmaf(x.y, a.y, aA.y);
        aA.z = fmaf(x.z, a.z, aA.z);  aA.w = fmaf(x.w, a.w, aA.w);
        aB.x = fmaf(x.x, bb.x, aB.x); aB.y = fmaf(x.y, bb.y, aB.y);
        aB.z = fmaf(x.z, bb.z, aB.z); aB.w = fmaf(x.w, bb.w, aB.w);
        aS.x = fmaf(x.x, x.x, aS.x);  aS.y = fmaf(x.y, x.y, aS.y);
        aS.z = fmaf(x.z, x.z, aS.z);  aS.w = fmaf(x.w, x.w, aS.w);
    }
    const float dA = aA.x + aA.y + aA.z + aA.w;
    const float dB = aB.x + aB.y + aB.z + aB.w;
    const float ns = aS.x + aS.y + aS.z + aS.w;
    const float rnj = 1.0f / fmaxf(sqrtf(ns), 1e-8f);
    rn_s[j] = rnj;

    // ordinal class positions
    float cp[NCL];
    cp[0] = 0.0f;
#pragma unroll
    for (int c = 0; c < NCL - 1; c++) cp[c + 1] = cp[c] + log1pf(expf(draw[c]));
    const int tiA = target[iA], tiB = target[iB];
    const float cpA = cp[tiA], cpB = cp[tiB];
    const int tj = target[j];
    const float cpj = cp[tj];
    __syncthreads();

    const float rniA = rn_s[iA], rniB = rn_s[iB];

    {   // anchor A setup
        float c0 = dA * rniA * rnj;
        bool n0 = (tj != tiA);
        ckA[j] = c0;
        ((float*)v4sA)[j] = n0 ? (c0 + fabsf(cpA - cpj)) : -1e30f;
        if (!n0 && j != iA) pkA[atomicAdd(&pcA, 1u)] = j;
        redi[tid] = (n0 ? 1 : 0);
    }
    {   // anchor B setup (negcounts packed: A low 16, B high 16)
        float c0 = dB * rniB * rnj;
        bool n0 = (tj != tiB);
        ckB[j] = c0;
        ((float*)v4sB)[j] = n0 ? (c0 + fabsf(cpB - cpj)) : -1e30f;
        if (!n0 && j != iB) pkB[atomicAdd(&pcB, 1u)] = j;
        redi[tid] += (n0 ? 1 : 0) << 16;
    }
    __syncthreads();
    for (int s = 256; s > 0; s >>= 1) {
        if (tid < s) redi[tid] += redi[tid + s];
        __syncthreads();
    }
    const int negA = redi[0] & 0xffff;
    const int negB = redi[0] >> 16;
    const unsigned int nposA = pcA, nposB = pcB;
    __syncthreads();

    // pass1 split: 32 k-lanes x 16 j-chunks (32 j's each, cached in VGPRs)
    const int kl = tid & 31, jc = tid >> 5;
    const float denA = (float)(negA > 1 ? negA : 1);
    const float denB = (float)(negB > 1 ? negB : 1);
    float contrib = 0.0f;
    int nzc = 0;

    {   // anchor A
        float4 vj[8];
#pragma unroll
        for (int t = 0; t < 8; t++) vj[t] = v4sA[jc * 8 + t];
        for (unsigned int p = kl; p < nposA; p += 32) {
            const float ckp = ckA[pkA[p]];
            float s0 = 0.0f, s1 = 0.0f;
#pragma unroll
            for (int t = 0; t < 8; t++) {
                float4 w = vj[t];
                s0 += fmaxf(w.x - ckp, 0.0f) + fmaxf(w.y - ckp, 0.0f);
                s1 += fmaxf(w.z - ckp, 0.0f) + fmaxf(w.w - ckp, 0.0f);
            }
            spart[p * 17 + jc] = s0 + s1;
        }
        __syncthreads();
        for (unsigned int p = tid; p < nposA; p += 512) {
            float s = 0.0f;
#pragma unroll
            for (int q = 0; q < 16; q++) s += spart[p * 17 + q];
            contrib += s / denA;
            if (s != 0.0f) nzc++;
        }
        __syncthreads();
    }
    {   // anchor B
        float4 vj[8];
#pragma unroll
        for (int t = 0; t < 8; t++) vj[t] = v4sB[jc * 8 + t];
        for (unsigned int p = kl; p < nposB; p += 32) {
            const float ckp = ckB[pkB[p]];
            float s0 = 0.0f, s1 = 0.0f;
#pragma unroll
            for (int t = 0; t < 8; t++) {
                float4 w = vj[t];
                s0 += fmaxf(w.x - ckp, 0.0f) + fmaxf(w.y - ckp, 0.0f);
                s1 += fmaxf(w.z - ckp, 0.0f) + fmaxf(w.w - ckp, 0.0f);
            }
            spart[p * 17 + jc] = s0 + s1;
        }
        __syncthreads();
        for (unsigned int p = tid; p < nposB; p += 512) {
            float s = 0.0f;
#pragma unroll
            for (int q = 0; q < 16; q++) s += spart[p * 17 + q];
            contrib += s / denB;
            if (s != 0.0f) nzc++;
        }
    }

    // ---- combined reduction + ticket finalize ----
    redf[tid] = contrib;
    redi[tid] = nzc;
    __syncthreads();
    for (int s = 256; s > 0; s >>= 1) {
        if (tid < s) { redf[tid] += redf[tid + s]; redi[tid] += redi[tid + s]; }
        __syncthreads();
    }
    if (tid == 0) {
        if (redf[0] != 0.0f || redi[0] != 0) {
            atomicAdd(gsum, redf[0]);
            atomicAdd(gnz, (unsigned int)redi[0]);
        }
        __threadfence();
        unsigned int t = atomicAdd(ticket, 1u);
        if (t == (unsigned int)(NBLK - 1)) {
            float s = atomicAdd(gsum, 0.0f);
            unsigned int n = atomicAdd(gnz, 0u);
            out[0] = s / (float)(n > 1u ? n : 1u);
        }
    }
}

extern "C" void kernel_launch(void* const* d_in, const int* in_sizes, int n_in,
                              void* d_out, int out_size, void* d_ws, size_t ws_size,
                              hipStream_t stream) {
    const float* pred   = (const float*)d_in[0];
    const float* draw   = (const float*)d_in[1];
    const int*   target = (const int*)d_in[2];
    float* out = (float*)d_out;

    unsigned int* ctrl = (unsigned int*)d_ws;   // 4 words, only ws use

    hipMemsetAsync(ctrl, 0, 4 * sizeof(unsigned int), stream);
    hipLaunchKernelGGL(k_all, dim3(NBLK), dim3(512), 0, stream,
                       pred, target, draw, ctrl, out);
}

// Round 10
// 86.839 us; speedup vs baseline: 1.7981x; 1.1913x over previous
//
#include <hip/hip_runtime.h>
#include <math.h>

#define NS 512
#define DE 512
#define NCL 5
#define NBLK 256

// ctrl words: [0]=gsum(f32) [1]=gnz [2]=ticket [3]=spare  (zeroed by memset node)

// ---------------------------------------------------------------------------
// Single fused kernel, 512 threads/block. Block b handles anchors iA=b,
// iB=b+256. Phase 1: coalesced triple-dot — wave w covers rows [64w,64w+64),
// 4 rows/step (16 lanes per row, 4-line runs instead of 64-line scatter),
// anchor rows cached in VGPR fragments, 16-lane butterfly reduce, leader
// writes raw dots + rn to LDS. Phase 2: R9-proven loss + ticket finalize.
// No intermediate global buffers.
// ---------------------------------------------------------------------------
__global__ __launch_bounds__(512) void k_all(const float* __restrict__ pred,
                                             const int* __restrict__ target,
                                             const float* __restrict__ draw,
                                             unsigned int* __restrict__ ctrl,
                                             float* __restrict__ out) {
    const int b = blockIdx.x;
    const int tid = threadIdx.x;
    const int iA = b, iB = b + 256;

    __shared__ float  rn_s[NS];
    __shared__ float  ckA[NS], ckB[NS];        // raw dots, then cos in place
    __shared__ float4 v4sA[NS / 4], v4sB[NS / 4];
    __shared__ int    pkA[NS], pkB[NS];
    __shared__ float  spart[NS * 17];          // 34 KB
    __shared__ float  redf[512];
    __shared__ int    redi[512];
    __shared__ unsigned int pcA, pcB;

    float* gsum = (float*)ctrl;
    unsigned int* gnz    = ctrl + 1;
    unsigned int* ticket = ctrl + 2;

    if (tid == 0) { pcA = 0u; pcB = 0u; }

    // ================= phase 1: coalesced triple dots =================
    const int w = tid >> 6, lane = tid & 63;
    const int g = lane >> 4, s = lane & 15;

    const float4* pA = (const float4*)&pred[(size_t)iA * DE];
    const float4* pB = (const float4*)&pred[(size_t)iB * DE];
    float4 fA[8], fB[8];
#pragma unroll
    for (int p = 0; p < 8; p++) { fA[p] = pA[p * 16 + s]; fB[p] = pB[p * 16 + s]; }

#pragma unroll 4
    for (int t = 0; t < 16; t++) {
        const int j = w * 64 + t * 4 + g;
        const float4* rj = (const float4*)&pred[(size_t)j * DE];
        float aA = 0.0f, aB = 0.0f, aS = 0.0f;
#pragma unroll
        for (int p = 0; p < 8; p++) {
            float4 x = rj[p * 16 + s];
            aA = fmaf(x.x, fA[p].x, aA); aA = fmaf(x.y, fA[p].y, aA);
            aA = fmaf(x.z, fA[p].z, aA); aA = fmaf(x.w, fA[p].w, aA);
            aB = fmaf(x.x, fB[p].x, aB); aB = fmaf(x.y, fB[p].y, aB);
            aB = fmaf(x.z, fB[p].z, aB); aB = fmaf(x.w, fB[p].w, aB);
            aS = fmaf(x.x, x.x, aS);     aS = fmaf(x.y, x.y, aS);
            aS = fmaf(x.z, x.z, aS);     aS = fmaf(x.w, x.w, aS);
        }
        // reduce across the 16-lane group (masks stay within the group)
#pragma unroll
        for (int m = 1; m <= 8; m <<= 1) {
            aA += __shfl_xor(aA, m);
            aB += __shfl_xor(aB, m);
            aS += __shfl_xor(aS, m);
        }
        if (s == 0) {
            ckA[j] = aA;
            ckB[j] = aB;
            rn_s[j] = 1.0f / fmaxf(sqrtf(aS), 1e-8f);
        }
    }

    // ordinal class positions
    float cp[NCL];
    cp[0] = 0.0f;
#pragma unroll
    for (int c = 0; c < NCL - 1; c++) cp[c + 1] = cp[c] + log1pf(expf(draw[c]));
    const int tiA = target[iA], tiB = target[iB];
    const float cpA = cp[tiA], cpB = cp[tiB];
    const int j = tid;
    const int tj = target[j];
    const float cpj = cp[tj];
    __syncthreads();

    // ================= phase 2: loss setup (thread tid = row tid) ==========
    const float rniA = rn_s[iA], rniB = rn_s[iB], rnj = rn_s[j];
    {   // anchor A
        float c0 = ckA[j] * rniA * rnj;
        bool n0 = (tj != tiA);
        ckA[j] = c0;
        ((float*)v4sA)[j] = n0 ? (c0 + fabsf(cpA - cpj)) : -1e30f;
        if (!n0 && j != iA) pkA[atomicAdd(&pcA, 1u)] = j;
        redi[tid] = (n0 ? 1 : 0);
    }
    {   // anchor B (negcounts packed: A low 16, B high 16)
        float c0 = ckB[j] * rniB * rnj;
        bool n0 = (tj != tiB);
        ckB[j] = c0;
        ((float*)v4sB)[j] = n0 ? (c0 + fabsf(cpB - cpj)) : -1e30f;
        if (!n0 && j != iB) pkB[atomicAdd(&pcB, 1u)] = j;
        redi[tid] += (n0 ? 1 : 0) << 16;
    }
    __syncthreads();
    for (int s2 = 256; s2 > 0; s2 >>= 1) {
        if (tid < s2) redi[tid] += redi[tid + s2];
        __syncthreads();
    }
    const int negA = redi[0] & 0xffff;
    const int negB = redi[0] >> 16;
    const unsigned int nposA = pcA, nposB = pcB;
    __syncthreads();

    // pass1 split: 32 k-lanes x 16 j-chunks (32 j's each, cached in VGPRs)
    const int kl = tid & 31, jc = tid >> 5;
    const float denA = (float)(negA > 1 ? negA : 1);
    const float denB = (float)(negB > 1 ? negB : 1);
    float contrib = 0.0f;
    int nzc = 0;

    {   // anchor A
        float4 vj[8];
#pragma unroll
        for (int t = 0; t < 8; t++) vj[t] = v4sA[jc * 8 + t];
        for (unsigned int p = kl; p < nposA; p += 32) {
            const float ckp = ckA[pkA[p]];
            float s0 = 0.0f, s1 = 0.0f;
#pragma unroll
            for (int t = 0; t < 8; t++) {
                float4 wv = vj[t];
                s0 += fmaxf(wv.x - ckp, 0.0f) + fmaxf(wv.y - ckp, 0.0f);
                s1 += fmaxf(wv.z - ckp, 0.0f) + fmaxf(wv.w - ckp, 0.0f);
            }
            spart[p * 17 + jc] = s0 + s1;
        }
        __syncthreads();
        for (unsigned int p = tid; p < nposA; p += 512) {
            float s0 = 0.0f;
#pragma unroll
            for (int q = 0; q < 16; q++) s0 += spart[p * 17 + q];
            contrib += s0 / denA;
            if (s0 != 0.0f) nzc++;
        }
        __syncthreads();
    }
    {   // anchor B
        float4 vj[8];
#pragma unroll
        for (int t = 0; t < 8; t++) vj[t] = v4sB[jc * 8 + t];
        for (unsigned int p = kl; p < nposB; p += 32) {
            const float ckp = ckB[pkB[p]];
            float s0 = 0.0f, s1 = 0.0f;
#pragma unroll
            for (int t = 0; t < 8; t++) {
                float4 wv = vj[t];
                s0 += fmaxf(wv.x - ckp, 0.0f) + fmaxf(wv.y - ckp, 0.0f);
                s1 += fmaxf(wv.z - ckp, 0.0f) + fmaxf(wv.w - ckp, 0.0f);
            }
            spart[p * 17 + jc] = s0 + s1;
        }
        __syncthreads();
        for (unsigned int p = tid; p < nposB; p += 512) {
            float s0 = 0.0f;
#pragma unroll
            for (int q = 0; q < 16; q++) s0 += spart[p * 17 + q];
            contrib += s0 / denB;
            if (s0 != 0.0f) nzc++;
        }
    }

    // ---- combined reduction + ticket finalize ----
    redf[tid] = contrib;
    redi[tid] = nzc;
    __syncthreads();
    for (int s2 = 256; s2 > 0; s2 >>= 1) {
        if (tid < s2) { redf[tid] += redf[tid + s2]; redi[tid] += redi[tid + s2]; }
        __syncthreads();
    }
    if (tid == 0) {
        if (redf[0] != 0.0f || redi[0] != 0) {
            atomicAdd(gsum, redf[0]);
            atomicAdd(gnz, (unsigned int)redi[0]);
        }
        __threadfence();
        unsigned int t = atomicAdd(ticket, 1u);
        if (t == (unsigned int)(NBLK - 1)) {
            float s0 = atomicAdd(gsum, 0.0f);
            unsigned int n = atomicAdd(gnz, 0u);
            out[0] = s0 / (float)(n > 1u ? n : 1u);
        }
    }
}

extern "C" void kernel_launch(void* const* d_in, const int* in_sizes, int n_in,
                              void* d_out, int out_size, void* d_ws, size_t ws_size,
                              hipStream_t stream) {
    const float* pred   = (const float*)d_in[0];
    const float* draw   = (const float*)d_in[1];
    const int*   target = (const int*)d_in[2];
    float* out = (float*)d_out;

    unsigned int* ctrl = (unsigned int*)d_ws;   // 4 words, only ws use

    hipMemsetAsync(ctrl, 0, 4 * sizeof(unsigned int), stream);
    hipLaunchKernelGGL(k_all, dim3(NBLK), dim3(512), 0, stream,
                       pred, target, draw, ctrl, out);
}